// Round 6
// baseline (2341.387 us; speedup 1.0000x reference)
//
#include <hip/hip_runtime.h>
#include <math.h>

#define DI __device__ __forceinline__

constexpr int B = 16, H = 41, W = 40, C = 48, M1 = 12, M2 = 12, NL = 4;
constexpr int HW = H * W;                  // 1640
constexpr float EPS = 1e-5f;
constexpr float PI_F = 3.14159265358979323846f;

// ---------------- static device scratch (compile-time shapes) ----------------
__device__ float  g_h[2][B * C * HW];      // ping-pong activations [b][c][hw]
__device__ float2 g_alpha[B * C * HW];     // fft2(inorm(h))
__device__ float2 g_inv1t[C * C * H * 16]; // transposed inv1 [pk][o*16+p] (pad 16)
__device__ float2 g_inv2[C * C * M2 * W];  // [i*C+k][q][x]
__device__ float2 g_E1[C * C * M1 * H];    // exp(p1 * TX)  [pk][p][z]
__device__ float2 g_E2[C * C * M2 * W];    // exp(p2 * TY)  [pk][q][x]
__device__ float2 g_S[C * C * HW];         // [i*C+k][o*W+x]
__device__ float2 g_res1[B * C * HW];
__device__ float  g_x1[B * C * HW];        // pr2d output accumulator (real)
__device__ float2 g_r2[B * C * M1 * M2];
__device__ float2 g_Zr[C * C][B * M1 * M2]; // per-(i,k) res-scaled Z, reduced over i by k_r2b
__device__ float  g_xpart[3][B * C][HW];   // k_x2p partial sums over ci-thirds
__device__ float  g_mu[B * C];
__device__ float  g_rstd[B * C];
__device__ float2 g_wfh[H * H];            // e^{-2pi i o h / H}
__device__ float2 g_wfw[W * W];            // e^{-2pi i x w / W}

// ---------------- complex helpers ----------------
DI float2 cmadd(float2 a, float2 b, float2 acc) {
    acc.x = fmaf(a.x, b.x, fmaf(-a.y, b.y, acc.x));
    acc.y = fmaf(a.x, b.y, fmaf(a.y, b.x, acc.y));
    return acc;
}
DI float2 cmul(float2 a, float2 b) {
    return make_float2(a.x * b.x - a.y * b.y, a.x * b.y + a.y * b.x);
}

// ---------------- twiddle tables ----------------
__global__ void k_tw() {
    int tid = blockIdx.x * 256 + threadIdx.x;
    if (tid < H * H) {
        int o = tid / H, h = tid % H;
        float ph = -2.0f * PI_F * (float)((o * h) % H) / (float)H;
        float s, c; sincosf(ph, &s, &c);
        g_wfh[tid] = make_float2(c, s);
    }
    int t2 = tid - H * H;
    if (t2 >= 0 && t2 < W * W) {
        int o = t2 / W, w = t2 % W;
        float ph = -2.0f * PI_F * (float)((o * w) % W) / (float)W;
        float s, c; sincosf(ph, &s, &c);
        g_wfw[t2] = make_float2(c, s);
    }
}

// ---------------- fc0 + grid concat ----------------
__global__ void k_fc0(const float* __restrict__ x, const float* __restrict__ w,
                      const float* __restrict__ bias) {
    int idx = blockIdx.x * 256 + threadIdx.x;
    if (idx >= B * C * HW) return;
    int hw = idx % HW; int bc = idx / HW; int c = bc % C; int b = bc / C;
    int hh = hw / W, ww = hw % W;
    float xv = x[b * HW + hw];
    float gx = hh * (1.0f / (H - 1));
    float gy = ww * (1.0f / (W - 1));
    g_h[0][idx] = fmaf(w[c * 3 + 0], xv, fmaf(w[c * 3 + 1], gx, fmaf(w[c * 3 + 2], gy, bias[c])));
}

// ---------------- instance-norm + fft2 (per b,c), 2 outputs/thread ----------------
__global__ __launch_bounds__(256) void k_fft(int src) {
    int bid = blockIdx.x;                  // b*C + c
    const float* hp = &g_h[src][(size_t)bid * HW];
    __shared__ float sh[HW];
    __shared__ float2 st[HW];
    __shared__ float red[8];
    int tid = threadIdx.x;
    float s = 0.f, ss = 0.f;
    for (int i = tid; i < HW; i += 256) { float v = hp[i]; sh[i] = v; s += v; ss += v * v; }
    for (int off = 32; off; off >>= 1) { s += __shfl_down(s, off); ss += __shfl_down(ss, off); }
    if ((tid & 63) == 0) { red[tid >> 6] = s; red[4 + (tid >> 6)] = ss; }
    __syncthreads();
    if (tid == 0) {
        float S = red[0] + red[1] + red[2] + red[3];
        float SS = red[4] + red[5] + red[6] + red[7];
        float mean = S * (1.0f / HW);
        float var = SS * (1.0f / HW) - mean * mean;
        red[0] = mean; red[1] = rsqrtf(var + EPS);
    }
    __syncthreads();
    float mean = red[0], rstd = red[1];
    for (int i = tid; i < HW; i += 256) sh[i] = (sh[i] - mean) * rstd;
    __syncthreads();
    // row DFT over h, paired o: st[o*W+w] = sum_h wfh[o,h] * sh[h,w]
    for (int i = tid; i < 21 * W; i += 256) {
        int o0 = (i / W) * 2, w = i % W;
        bool pair = (o0 + 1) < H;
        float2 a0 = make_float2(0.f, 0.f), a1 = make_float2(0.f, 0.f);
        for (int h = 0; h < H; h++) {
            float v = sh[h * W + w];
            float2 t0 = g_wfh[o0 * H + h];
            a0.x = fmaf(t0.x, v, a0.x); a0.y = fmaf(t0.y, v, a0.y);
            if (pair) {
                float2 t1 = g_wfh[o0 * H + H + h];
                a1.x = fmaf(t1.x, v, a1.x); a1.y = fmaf(t1.y, v, a1.y);
            }
        }
        st[o0 * W + w] = a0;
        if (pair) st[(o0 + 1) * W + w] = a1;
    }
    __syncthreads();
    // col DFT over w, paired x: alpha[o*W+x] = sum_w st[o,w] * wfw[x,w]
    float2* ap = &g_alpha[(size_t)bid * HW];
    for (int i = tid; i < H * 20; i += 256) {
        int o = i / 20, x0 = (i % 20) * 2;
        float2 a0 = make_float2(0.f, 0.f), a1 = make_float2(0.f, 0.f);
        for (int w = 0; w < W; w++) {
            float2 sv = st[o * W + w];
            a0 = cmadd(sv, g_wfw[x0 * W + w], a0);
            a1 = cmadd(sv, g_wfw[x0 * W + W + w], a1);
        }
        ap[o * W + x0] = a0;
        ap[o * W + x0 + 1] = a1;
    }
}

// ---------------- k_tbS: fused pole tables + S[i,k,o,x] ----------------
__global__ __launch_bounds__(256) void k_tbS(const float* __restrict__ p1, const float* __restrict__ p2,
                                             const float* __restrict__ res_in, int l) {
    int pk = blockIdx.x;                   // i*C + k
    int tid = threadIdx.x;
    __shared__ float2 sinv1[M1 * H];       // [p*H+o]
    __shared__ float2 sinv2[M2 * W];       // [q*W+x]
    __shared__ float2 sT[M1 * W];
    __shared__ float2 sres[M1 * M2];
    const float* pp1 = p1 + (size_t)(l * C * C + pk) * M1 * 2;
    const float* pp2 = p2 + (size_t)(l * C * C + pk) * M2 * 2;
    for (int t = tid; t < M1 * H; t += 256) {
        int p = t / H, o = t % H;
        float pr = pp1[p * 2], pi = pp1[p * 2 + 1];
        int ko = (o <= H / 2) ? o : o - H;           // fftfreq, H=41 odd
        float lam = (40.0f / 41.0f) * (float)ko;     // Im(LAM1)
        float a = -pr, b = lam - pi;
        float d = 1.0f / (a * a + b * b);
        float2 inv = make_float2(a * d, -b * d);
        sinv1[t] = inv;
        g_inv1t[(size_t)pk * (H * 16) + o * 16 + p] = inv;
        float tt = o * (2.0f * PI_F / (H - 1));      // TX[z]
        float er = expf(pr * tt);
        float sn, cs; sincosf(pi * tt, &sn, &cs);
        g_E1[(size_t)pk * (M1 * H) + t] = make_float2(er * cs, er * sn);
    }
    for (int t = tid; t < M2 * W; t += 256) {
        int q = t / W, x = t % W;
        float pr = pp2[q * 2], pi = pp2[q * 2 + 1];
        int kx = (x < W / 2) ? x : x - W;            // fftfreq, W=40 even
        float lam = (2.0f * PI_F * 39.0f / 600.0f) * (float)kx;  // Im(LAM2)
        float a = -pr, b = lam - pi;
        float d = 1.0f / (a * a + b * b);
        float2 inv = make_float2(a * d, -b * d);
        sinv2[t] = inv;
        g_inv2[(size_t)pk * (M2 * W) + t] = inv;
        float tt = x * (15.0f / (W - 1));            // TY[x]
        float er = expf(pr * tt);
        float sn, cs; sincosf(pi * tt, &sn, &cs);
        g_E2[(size_t)pk * (M2 * W) + t] = make_float2(er * cs, er * sn);
    }
    const float2* rp = (const float2*)res_in + (size_t)(l * C * C + pk) * M1 * M2;
    for (int t = tid; t < M1 * M2; t += 256) sres[t] = rp[t];
    __syncthreads();
    // T[p,x] = sum_q res[p,q] inv2[q,x]
    for (int t = tid; t < M1 * W; t += 256) {
        int p = t / W, x = t % W;
        float2 acc = make_float2(0.f, 0.f);
        for (int q = 0; q < M2; q++) acc = cmadd(sres[p * M2 + q], sinv2[q * W + x], acc);
        sT[t] = acc;
    }
    __syncthreads();
    // S[o,x] = sum_p inv1[p,o] * T[p,x]
    float2* sp = &g_S[(size_t)pk * HW];
    for (int t = tid; t < HW; t += 256) {
        int o = t / W, x = t % W;
        float2 acc = make_float2(0.f, 0.f);
        for (int p = 0; p < M1; p++) acc = cmadd(sinv1[p * H + o], sT[p * W + x], acc);
        sp[t] = acc;
    }
}

// ---------------- res1[b,k,hw-half] = sum_i alpha[b,i,·] * S[i,k,·] ----------------
__global__ __launch_bounds__(256) void k_res1() {
    // XCD-aware remap: same-k blocks cluster on one XCD (S k-slice L2-resident)
    int bid = blockIdx.x;
    int xcd = bid & 7, idx = bid >> 3;             // idx 0..191
    int half = idx & 1; idx >>= 1;                 // 0..95
    int k = (idx / B) * 8 + xcd;
    int b = idx % B;
    int base = half * (HW / 2);                    // 820 per half
    int tid = threadIdx.x;
    float2 acc[4];
#pragma unroll
    for (int j = 0; j < 4; j++) acc[j] = make_float2(0.f, 0.f);
    for (int i = 0; i < C; i++) {
        const float2* ap = &g_alpha[(size_t)(b * C + i) * HW + base];
        const float2* sp = &g_S[(size_t)(i * C + k) * HW + base];
#pragma unroll
        for (int j = 0; j < 4; j++) {
            int idx2 = tid + j * 256;
            if (idx2 < HW / 2) acc[j] = cmadd(ap[idx2], sp[idx2], acc[j]);
        }
    }
    float2* rp = &g_res1[(size_t)(b * C + k) * HW + base];
#pragma unroll
    for (int j = 0; j < 4; j++) { int idx2 = tid + j * 256; if (idx2 < HW / 2) rp[idx2] = acc[j]; }
}

// ---------------- x1 = ifft2(res1).real, 2 outputs/thread ----------------
__global__ __launch_bounds__(256) void k_ifft() {
    int bid = blockIdx.x; int tid = threadIdx.x;
    __shared__ float2 s0[HW], s1[HW];
    const float2* rp = &g_res1[(size_t)bid * HW];
    for (int i = tid; i < HW; i += 256) s0[i] = rp[i];
    __syncthreads();
    // inverse over o, paired h: s1[h,x] = sum_o s0[o,x] * conj(wfh[o,h])
    for (int i = tid; i < 21 * W; i += 256) {
        int h0 = (i / W) * 2, x = i % W;
        bool pair = (h0 + 1) < H;
        float2 a0 = make_float2(0.f, 0.f), a1 = make_float2(0.f, 0.f);
        for (int o = 0; o < H; o++) {
            float2 v = s0[o * W + x];
            float2 t0 = g_wfh[o * H + h0];
            a0.x = fmaf(v.x, t0.x, fmaf(v.y, t0.y, a0.x));
            a0.y = fmaf(v.y, t0.x, fmaf(-v.x, t0.y, a0.y));
            if (pair) {
                float2 t1 = g_wfh[o * H + h0 + 1];
                a1.x = fmaf(v.x, t1.x, fmaf(v.y, t1.y, a1.x));
                a1.y = fmaf(v.y, t1.x, fmaf(-v.x, t1.y, a1.y));
            }
        }
        s1[h0 * W + x] = a0;
        if (pair) s1[(h0 + 1) * W + x] = a1;
    }
    __syncthreads();
    // inverse over x, paired w, real part only
    float* xp = &g_x1[(size_t)bid * HW];
    for (int i = tid; i < H * 20; i += 256) {
        int h = i / 20, w0 = (i % 20) * 2;
        float a0 = 0.f, a1 = 0.f;
        for (int x = 0; x < W; x++) {
            float2 v = s1[h * W + x];
            float2 t0 = g_wfw[x * W + w0];
            float2 t1 = g_wfw[x * W + w0 + 1];
            a0 = fmaf(v.x, t0.x, fmaf(v.y, t0.y, a0));
            a1 = fmaf(v.x, t1.x, fmaf(v.y, t1.y, a1));
        }
        xp[h * W + w0]     = a0 * (1.0f / (H * W));
        xp[h * W + w0 + 1] = a1 * (1.0f / (H * W));
    }
}

// ---------------- k_r2a v4: per (i,k,b-chunk): Zr = res ⊙ (inv1 @ alpha @ inv2^T) ----------
// grid C*C*4 = 9216. Y: 160 thr (4b x 40x), 12 accs, float4 inv1t reads. Z: 192 thr.
// LDS ~21KB -> 7 blocks/CU. 3 barriers per block.
__global__ __launch_bounds__(256) void k_r2a(const float* __restrict__ res_in, int l) {
    // XCD-aware remap: same-i blocks on one XCD (alpha[:,i] slices L2-resident)
    int bid = blockIdx.x;
    int xcd = bid & 7, idx = bid >> 3;             // idx 0..1151
    int i = (idx / (C * 4)) * 8 + xcd;             // 6 i's per XCD
    int rem = idx % (C * 4);
    int k = rem >> 2;
    int bc = rem & 3;                              // b-chunk: b = bc*4 .. bc*4+3
    int pk = i * C + k;
    int tid = threadIdx.x;
    __shared__ float2 sY[4 * M1 * 41];             // 15.7 KB
    __shared__ float2 si1t[H * 16];                // transposed inv1 [o][p], 16-padded
    __shared__ float2 si2[M2 * 41];                // [q*41 + x]
    __shared__ float2 sres[M1 * M2];
    for (int t = tid; t < H * 16; t += 256) si1t[t] = g_inv1t[(size_t)pk * (H * 16) + t];
    for (int t = tid; t < M2 * W; t += 256) {
        int q = t / W, x = t % W;
        si2[q * 41 + x] = g_inv2[(size_t)pk * (M2 * W) + t];
    }
    const float2* rp = (const float2*)res_in + (size_t)(l * C * C + pk) * M1 * M2;
    for (int t = tid; t < M1 * M2; t += 256) sres[t] = rp[t];
    __syncthreads();
    // ---- Y phase ----
    if (tid < 160) {
        int bloc = tid / 40, x = tid % 40;
        int b = bc * 4 + bloc;
        const float2* ap = &g_alpha[(size_t)(b * C + i) * HW + x];
        float2 yacc[12];
#pragma unroll
        for (int p = 0; p < 12; p++) yacc[p] = make_float2(0.f, 0.f);
        for (int o = 0; o < H; o++) {
            float2 a = ap[o * W];
            const float4* e4 = (const float4*)&si1t[o * 16];
#pragma unroll
            for (int j = 0; j < 6; j++) {
                float4 ee = e4[j];
                yacc[2 * j]     = cmadd(make_float2(ee.x, ee.y), a, yacc[2 * j]);
                yacc[2 * j + 1] = cmadd(make_float2(ee.z, ee.w), a, yacc[2 * j + 1]);
            }
        }
#pragma unroll
        for (int p = 0; p < 12; p++) sY[(bloc * M1 + p) * 41 + x] = yacc[p];
    }
    __syncthreads();
    // ---- Z phase ----
    if (tid < 192) {
        int bloc = tid / 48, rem2 = tid % 48;
        int p = rem2 >> 2, qq = rem2 & 3;
        int q0 = qq * 3;
        float2 zacc[3];
#pragma unroll
        for (int j = 0; j < 3; j++) zacc[j] = make_float2(0.f, 0.f);
        const float2* yrow = &sY[(bloc * M1 + p) * 41];
        for (int x = 0; x < W; x++) {
            float2 y = yrow[x];
#pragma unroll
            for (int j = 0; j < 3; j++) zacc[j] = cmadd(y, si2[(q0 + j) * 41 + x], zacc[j]);
        }
        int b = bc * 4 + bloc;
        float2* out = &g_Zr[pk][b * (M1 * M2) + p * M2 + q0];
#pragma unroll
        for (int j = 0; j < 3; j++) out[j] = cmul(sres[p * M2 + q0 + j], zacc[j]);
    }
}

// ---------------- k_r2b: r2[b,k,p,q] = sum_i Zr[i*C+k][b,p,q] ----------------
__global__ __launch_bounds__(256) void k_r2b() {
    int t = blockIdx.x * 256 + threadIdx.x;        // < B*C*144
    if (t >= B * C * M1 * M2) return;
    int pq = t % (M1 * M2);
    int k = (t / (M1 * M2)) % C;
    int b = t / (M1 * M2 * C);
    float2 acc = make_float2(0.f, 0.f);
    for (int i = 0; i < C; i++) {
        float2 v = g_Zr[i * C + k][b * (M1 * M2) + pq];
        acc.x += v.x; acc.y += v.y;
    }
    g_r2[(size_t)(b * C + k) * (M1 * M2) + pq] = acc;
}

// ---------------- k_x2p: partial x2 over 16-ci chunk (part 0..2) ----------------
// grid 2304 = 8(xcd) * 3(part) * 96(k-chunk*b); LDS ~26KB -> 6 blocks/CU.
constexpr int XNCI = 2;
__global__ __launch_bounds__(256) void k_x2p() {
    int bid = blockIdx.x;
    int xcd = bid & 7, rest = bid >> 3;            // 0..287
    int part = rest % 3;
    int idx = rest / 3;                            // 0..95
    int k = (idx / B) * 8 + xcd;
    int b = idx % B;
    int tid = threadIdx.x;
    __shared__ float2 sE1[XNCI * M1 * 44];         // [jp][z], z-padded to 44 (zeros)
    __shared__ float2 sV [XNCI * M1 * 40];         // [jp][x]
    __shared__ float2 sE2[XNCI * M2 * 41];         // [jq][x]
    __shared__ float2 sr2[XNCI * M1 * M2];
    int xh = tid % 20, zq = tid / 20;              // active: tid<240
    int x0 = xh * 2, z0 = zq * 4;
    float accr[4][2];
#pragma unroll
    for (int zi = 0; zi < 4; zi++) { accr[zi][0] = 0.f; accr[zi][1] = 0.f; }

    int cg0 = part * (C / XNCI / 3);               // 8 cg groups per part
    for (int cg = cg0; cg < cg0 + C / XNCI / 3; cg++) {
        for (int t = tid; t < XNCI * M1 * 44; t += 256) {
            int j = t / (M1 * 44), rem = t % (M1 * 44);
            int p = rem / 44, z = rem % 44;
            sE1[t] = (z < H) ? g_E1[(size_t)((cg * XNCI + j) * C + k) * (M1 * H) + p * H + z]
                             : make_float2(0.f, 0.f);
        }
        for (int t = tid; t < XNCI * M2 * W; t += 256) {
            int j = t / (M2 * W), rem = t % (M2 * W);
            sE2[(t / W) * 41 + (t % W)] = g_E2[(size_t)((cg * XNCI + j) * C + k) * (M2 * W) + rem];
        }
        for (int t = tid; t < XNCI * M1 * M2; t += 256) {
            int j = t / (M1 * M2);
            sr2[t] = g_r2[(size_t)(b * C + cg * XNCI + j) * (M1 * M2) + (t % (M1 * M2))];
        }
        __syncthreads();
        // V[jp][x] = sum_q r2[j][p,q] * E2[j][q,x]
        for (int r = 0; r < 4; r++) {
            int id = tid + r * 256;
            if (id < XNCI * M1 * W) {
                int j = id / (M1 * W), rem = id % (M1 * W);
                int p = rem / W, x = rem % W;
                float2 a = make_float2(0.f, 0.f);
#pragma unroll
                for (int q = 0; q < M2; q++)
                    a = cmadd(sr2[j * (M1 * M2) + p * M2 + q], sE2[(j * M2 + q) * 41 + x], a);
                sV[(j * M1 + p) * 40 + x] = a;
            }
        }
        __syncthreads();
        // accr[z,x] += Re( E1[jp][z] * V[jp][x] )
        if (tid < 240 && z0 < H) {
            for (int jp = 0; jp < XNCI * M1; jp++) {
                float4 v  = *(const float4*)&sV[jp * 40 + x0];
                float4 eA = *(const float4*)&sE1[jp * 44 + z0];
                float4 eB = *(const float4*)&sE1[jp * 44 + z0 + 2];
                accr[0][0] = fmaf(eA.x, v.x, fmaf(-eA.y, v.y, accr[0][0]));
                accr[0][1] = fmaf(eA.x, v.z, fmaf(-eA.y, v.w, accr[0][1]));
                accr[1][0] = fmaf(eA.z, v.x, fmaf(-eA.w, v.y, accr[1][0]));
                accr[1][1] = fmaf(eA.z, v.z, fmaf(-eA.w, v.w, accr[1][1]));
                accr[2][0] = fmaf(eB.x, v.x, fmaf(-eB.y, v.y, accr[2][0]));
                accr[2][1] = fmaf(eB.x, v.z, fmaf(-eB.y, v.w, accr[2][1]));
                accr[3][0] = fmaf(eB.z, v.x, fmaf(-eB.w, v.y, accr[3][0]));
                accr[3][1] = fmaf(eB.z, v.z, fmaf(-eB.w, v.w, accr[3][1]));
            }
        }
        __syncthreads();
    }
    float* op = &g_xpart[part][b * C + k][0];
    if (tid < 240 && z0 < H) {
#pragma unroll
        for (int zi = 0; zi < 4; zi++) {
            int z = z0 + zi;
            if (z < H) { op[z * W + x0] = accr[zi][0]; op[z * W + x0 + 1] = accr[zi][1]; }
        }
    }
}

// ---------------- k_fin: pr = x1 + (sum parts)/(H*W); stats ----------------
__global__ __launch_bounds__(256) void k_fin() {
    int bid = blockIdx.x;                          // b*C + k
    int tid = threadIdx.x;
    __shared__ float red[8];
    float* xp = &g_x1[(size_t)bid * HW];
    const float* p0 = &g_xpart[0][bid][0];
    const float* p1 = &g_xpart[1][bid][0];
    const float* p2 = &g_xpart[2][bid][0];
    float s = 0.f, ss = 0.f;
    for (int i = tid; i < HW; i += 256) {
        float v = xp[i] + (p0[i] + p1[i] + p2[i]) * (1.0f / (H * W));
        xp[i] = v; s += v; ss += v * v;
    }
    for (int off = 32; off; off >>= 1) { s += __shfl_down(s, off); ss += __shfl_down(ss, off); }
    if ((tid & 63) == 0) { red[tid >> 6] = s; red[4 + (tid >> 6)] = ss; }
    __syncthreads();
    if (tid == 0) {
        float S = red[0] + red[1] + red[2] + red[3];
        float SS = red[4] + red[5] + red[6] + red[7];
        float mean = S * (1.0f / HW);
        float var = SS * (1.0f / HW) - mean * mean;
        g_mu[bid] = mean; g_rstd[bid] = rsqrtf(var + EPS);
    }
}

// ---------------- h_next = sin( inorm(pr) + conv(h) + conv_b ) ----------------
constexpr int TILE = 128;
constexpr int NTILE = (HW + TILE - 1) / TILE;   // 13
__global__ __launch_bounds__(256) void k_comb(const float* __restrict__ cw,
                                              const float* __restrict__ cb, int l, int src) {
    int b = blockIdx.x / NTILE;
    int t0 = (blockIdx.x % NTILE) * TILE;
    int tid = threadIdx.x;
    __shared__ float shh[C * TILE];
    __shared__ float scw[C * C];
    __shared__ float smu[C], srs[C], scb[C];
    for (int i = tid; i < C * C; i += 256) scw[i] = cw[l * C * C + i];
    for (int i = tid; i < C; i += 256) {
        smu[i] = g_mu[b * C + i]; srs[i] = g_rstd[b * C + i]; scb[i] = cb[l * C + i];
    }
    for (int i = tid; i < C * TILE; i += 256) {
        int c = i / TILE, t = i % TILE; int hw = t0 + t;
        shh[i] = (hw < HW) ? g_h[src][(size_t)(b * C + c) * HW + hw] : 0.f;
    }
    __syncthreads();
    for (int i = tid; i < C * TILE; i += 256) {
        int o = i / TILE, t = i % TILE; int hw = t0 + t;
        if (hw >= HW) continue;
        float acc = scb[o];
        for (int ci = 0; ci < C; ci++) acc = fmaf(scw[o * C + ci], shh[ci * TILE + t], acc);
        float prn = (g_x1[(size_t)(b * C + o) * HW + hw] - smu[o]) * srs[o];
        g_h[src ^ 1][(size_t)(b * C + o) * HW + hw] = sinf(prn + acc);
    }
}

// ---------------- head: out = fc2( sin(fc1(h)) ) ----------------
__global__ __launch_bounds__(256) void k_head(const float* __restrict__ w1, const float* __restrict__ b1,
                                              const float* __restrict__ w2, const float* __restrict__ b2,
                                              float* __restrict__ out, int src) {
    __shared__ float sw1[128 * C];
    __shared__ float sb1[128], sw2[2 * 128];
    int tid = threadIdx.x;
    for (int i = tid; i < 128 * C; i += 256) sw1[i] = w1[i];
    for (int i = tid; i < 128; i += 256) sb1[i] = b1[i];
    for (int i = tid; i < 256; i += 256) sw2[i] = w2[i];
    __syncthreads();
    int pt = blockIdx.x * 256 + tid;               // b*HW + hw
    if (pt >= B * HW) return;
    int b = pt / HW, hw = pt % HW;
    float hv[C];
#pragma unroll
    for (int c = 0; c < C; c++) hv[c] = g_h[src][(size_t)(b * C + c) * HW + hw];
    float o0 = b2[0], o1 = b2[1];
    for (int j = 0; j < 128; j++) {
        float a = sb1[j];
#pragma unroll
        for (int c = 0; c < C; c++) a = fmaf(sw1[j * C + c], hv[c], a);
        float sv = sinf(a);
        o0 = fmaf(sw2[j], sv, o0);
        o1 = fmaf(sw2[128 + j], sv, o1);
    }
    out[pt * 2 + 0] = o0; out[pt * 2 + 1] = o1;
}

// ---------------- launcher ----------------
extern "C" void kernel_launch(void* const* d_in, const int* in_sizes, int n_in,
                              void* d_out, int out_size, void* d_ws, size_t ws_size,
                              hipStream_t stream) {
    const float* x    = (const float*)d_in[0];
    const float* fc0w = (const float*)d_in[1];
    const float* fc0b = (const float*)d_in[2];
    const float* p1   = (const float*)d_in[3];
    const float* p2   = (const float*)d_in[4];
    const float* res  = (const float*)d_in[5];
    const float* cw   = (const float*)d_in[6];
    const float* cb   = (const float*)d_in[7];
    const float* w1   = (const float*)d_in[8];
    const float* b1   = (const float*)d_in[9];
    const float* w2   = (const float*)d_in[10];
    const float* b2   = (const float*)d_in[11];
    float* out = (float*)d_out;

    k_tw<<<(H * H + W * W + 255) / 256, 256, 0, stream>>>();
    k_fc0<<<(B * C * HW + 255) / 256, 256, 0, stream>>>(x, fc0w, fc0b);
    int src = 0;
    for (int l = 0; l < NL; l++) {
        k_fft<<<B * C, 256, 0, stream>>>(src);
        k_tbS<<<C * C, 256, 0, stream>>>(p1, p2, res, l);
        k_res1<<<B * C * 2, 256, 0, stream>>>();
        k_ifft<<<B * C, 256, 0, stream>>>();
        k_r2a<<<C * C * 4, 256, 0, stream>>>(res, l);
        k_r2b<<<(B * C * M1 * M2 + 255) / 256, 256, 0, stream>>>();
        k_x2p<<<3 * B * C, 256, 0, stream>>>();
        k_fin<<<B * C, 256, 0, stream>>>();
        k_comb<<<B * NTILE, 256, 0, stream>>>(cw, cb, l, src);
        src ^= 1;
    }
    k_head<<<(B * HW + 255) / 256, 256, 0, stream>>>(w1, b1, w2, b2, out, src);
}

// Round 7
// 2167.022 us; speedup vs baseline: 1.0805x; 1.0805x over previous
//
#include <hip/hip_runtime.h>
#include <math.h>

#define DI __device__ __forceinline__

constexpr int B = 16, H = 41, W = 40, C = 48, M1 = 12, M2 = 12, NL = 4;
constexpr int HW = H * W;                  // 1640
constexpr float EPS = 1e-5f;
constexpr float PI_F = 3.14159265358979323846f;

// ---------------- static device scratch (compile-time shapes) ----------------
__device__ float  g_h[2][B * C * HW];      // ping-pong activations [b][c][hw]
__device__ float2 g_alpha[B * C * HW];     // fft2(inorm(h))
__device__ float2 g_inv1t[C * C * H * 16]; // transposed inv1 [pk][o*16+p] (pad 16)
__device__ float2 g_inv2[C * C * M2 * W];  // [i*C+k][q][x]
__device__ float2 g_E1[C * C * M1 * H];    // exp(p1 * TX)  [pk][p][z]
__device__ float2 g_E2[C * C * M2 * W];    // exp(p2 * TY)  [pk][q][x]
__device__ float2 g_S[C * C * HW];         // [i*C+k][o*W+x]
__device__ float2 g_res1[B * C * HW];
__device__ float  g_x1[B * C * HW];        // pr2d output accumulator (real)
__device__ float2 g_r2[B * C * M1 * M2];
__device__ float2 g_Zr[C * C][B * M1 * M2]; // per-(i,k) res-scaled Z, reduced over i by k_r2b
__device__ float  g_xpart[3][B * C][HW];   // k_x2p partial sums over ci-thirds
__device__ float  g_mu[B * C];
__device__ float  g_rstd[B * C];
__device__ float2 g_wfh[H * H];            // e^{-2pi i o h / H}
__device__ float2 g_wfw[W * W];            // e^{-2pi i x w / W}

// ---------------- complex helpers ----------------
DI float2 cmadd(float2 a, float2 b, float2 acc) {
    acc.x = fmaf(a.x, b.x, fmaf(-a.y, b.y, acc.x));
    acc.y = fmaf(a.x, b.y, fmaf(a.y, b.x, acc.y));
    return acc;
}
DI float2 cmul(float2 a, float2 b) {
    return make_float2(a.x * b.x - a.y * b.y, a.x * b.y + a.y * b.x);
}

// ---------------- twiddle tables ----------------
__global__ void k_tw() {
    int tid = blockIdx.x * 256 + threadIdx.x;
    if (tid < H * H) {
        int o = tid / H, h = tid % H;
        float ph = -2.0f * PI_F * (float)((o * h) % H) / (float)H;
        float s, c; sincosf(ph, &s, &c);
        g_wfh[tid] = make_float2(c, s);
    }
    int t2 = tid - H * H;
    if (t2 >= 0 && t2 < W * W) {
        int o = t2 / W, w = t2 % W;
        float ph = -2.0f * PI_F * (float)((o * w) % W) / (float)W;
        float s, c; sincosf(ph, &s, &c);
        g_wfw[t2] = make_float2(c, s);
    }
}

// ---------------- fc0 + grid concat ----------------
__global__ void k_fc0(const float* __restrict__ x, const float* __restrict__ w,
                      const float* __restrict__ bias) {
    int idx = blockIdx.x * 256 + threadIdx.x;
    if (idx >= B * C * HW) return;
    int hw = idx % HW; int bc = idx / HW; int c = bc % C; int b = bc / C;
    int hh = hw / W, ww = hw % W;
    float xv = x[b * HW + hw];
    float gx = hh * (1.0f / (H - 1));
    float gy = ww * (1.0f / (W - 1));
    g_h[0][idx] = fmaf(w[c * 3 + 0], xv, fmaf(w[c * 3 + 1], gx, fmaf(w[c * 3 + 2], gy, bias[c])));
}

// ---------------- instance-norm + fft2 (per b,c), 2 outputs/thread ----------------
__global__ __launch_bounds__(256) void k_fft(int src) {
    int bid = blockIdx.x;                  // b*C + c
    const float* hp = &g_h[src][(size_t)bid * HW];
    __shared__ float sh[HW];
    __shared__ float2 st[HW];
    __shared__ float red[8];
    int tid = threadIdx.x;
    float s = 0.f, ss = 0.f;
    for (int i = tid; i < HW; i += 256) { float v = hp[i]; sh[i] = v; s += v; ss += v * v; }
    for (int off = 32; off; off >>= 1) { s += __shfl_down(s, off); ss += __shfl_down(ss, off); }
    if ((tid & 63) == 0) { red[tid >> 6] = s; red[4 + (tid >> 6)] = ss; }
    __syncthreads();
    if (tid == 0) {
        float S = red[0] + red[1] + red[2] + red[3];
        float SS = red[4] + red[5] + red[6] + red[7];
        float mean = S * (1.0f / HW);
        float var = SS * (1.0f / HW) - mean * mean;
        red[0] = mean; red[1] = rsqrtf(var + EPS);
    }
    __syncthreads();
    float mean = red[0], rstd = red[1];
    for (int i = tid; i < HW; i += 256) sh[i] = (sh[i] - mean) * rstd;
    __syncthreads();
    // row DFT over h, paired o: st[o*W+w] = sum_h wfh[o,h] * sh[h,w]
    for (int i = tid; i < 21 * W; i += 256) {
        int o0 = (i / W) * 2, w = i % W;
        bool pair = (o0 + 1) < H;
        float2 a0 = make_float2(0.f, 0.f), a1 = make_float2(0.f, 0.f);
        for (int h = 0; h < H; h++) {
            float v = sh[h * W + w];
            float2 t0 = g_wfh[o0 * H + h];
            a0.x = fmaf(t0.x, v, a0.x); a0.y = fmaf(t0.y, v, a0.y);
            if (pair) {
                float2 t1 = g_wfh[o0 * H + H + h];
                a1.x = fmaf(t1.x, v, a1.x); a1.y = fmaf(t1.y, v, a1.y);
            }
        }
        st[o0 * W + w] = a0;
        if (pair) st[(o0 + 1) * W + w] = a1;
    }
    __syncthreads();
    // col DFT over w, paired x: alpha[o*W+x] = sum_w st[o,w] * wfw[x,w]
    float2* ap = &g_alpha[(size_t)bid * HW];
    for (int i = tid; i < H * 20; i += 256) {
        int o = i / 20, x0 = (i % 20) * 2;
        float2 a0 = make_float2(0.f, 0.f), a1 = make_float2(0.f, 0.f);
        for (int w = 0; w < W; w++) {
            float2 sv = st[o * W + w];
            a0 = cmadd(sv, g_wfw[x0 * W + w], a0);
            a1 = cmadd(sv, g_wfw[x0 * W + W + w], a1);
        }
        ap[o * W + x0] = a0;
        ap[o * W + x0 + 1] = a1;
    }
}

// ---------------- k_tbS: fused pole tables + S[i,k,o,x] ----------------
// inv1t written COALESCED (o*16+p order) via LDS staging — r6's scatter write was ~8x amplified.
__global__ __launch_bounds__(256) void k_tbS(const float* __restrict__ p1, const float* __restrict__ p2,
                                             const float* __restrict__ res_in, int l) {
    int pk = blockIdx.x;                   // i*C + k
    int tid = threadIdx.x;
    __shared__ float2 sinv1[M1 * H];       // [p*H+o]
    __shared__ float2 sinv2[M2 * W];       // [q*W+x]
    __shared__ float2 sT[M1 * W];
    __shared__ float2 sres[M1 * M2];
    const float* pp1 = p1 + (size_t)(l * C * C + pk) * M1 * 2;
    const float* pp2 = p2 + (size_t)(l * C * C + pk) * M2 * 2;
    for (int t = tid; t < M1 * H; t += 256) {
        int p = t / H, o = t % H;
        float pr = pp1[p * 2], pi = pp1[p * 2 + 1];
        int ko = (o <= H / 2) ? o : o - H;           // fftfreq, H=41 odd
        float lam = (40.0f / 41.0f) * (float)ko;     // Im(LAM1)
        float a = -pr, b = lam - pi;
        float d = 1.0f / (a * a + b * b);
        float2 inv = make_float2(a * d, -b * d);
        sinv1[t] = inv;
        float tt = o * (2.0f * PI_F / (H - 1));      // TX[z]
        float er = expf(pr * tt);
        float sn, cs; sincosf(pi * tt, &sn, &cs);
        g_E1[(size_t)pk * (M1 * H) + t] = make_float2(er * cs, er * sn);
    }
    for (int t = tid; t < M2 * W; t += 256) {
        int q = t / W, x = t % W;
        float pr = pp2[q * 2], pi = pp2[q * 2 + 1];
        int kx = (x < W / 2) ? x : x - W;            // fftfreq, W=40 even
        float lam = (2.0f * PI_F * 39.0f / 600.0f) * (float)kx;  // Im(LAM2)
        float a = -pr, b = lam - pi;
        float d = 1.0f / (a * a + b * b);
        float2 inv = make_float2(a * d, -b * d);
        sinv2[t] = inv;
        g_inv2[(size_t)pk * (M2 * W) + t] = inv;
        float tt = x * (15.0f / (W - 1));            // TY[x]
        float er = expf(pr * tt);
        float sn, cs; sincosf(pi * tt, &sn, &cs);
        g_E2[(size_t)pk * (M2 * W) + t] = make_float2(er * cs, er * sn);
    }
    const float2* rp = (const float2*)res_in + (size_t)(l * C * C + pk) * M1 * M2;
    for (int t = tid; t < M1 * M2; t += 256) sres[t] = rp[t];
    __syncthreads();
    // coalesced transposed inv1 write: consecutive t -> consecutive addresses
    for (int t = tid; t < H * 16; t += 256) {
        int o = t >> 4, p = t & 15;
        g_inv1t[(size_t)pk * (H * 16) + t] = (p < M1) ? sinv1[p * H + o] : make_float2(0.f, 0.f);
    }
    // T[p,x] = sum_q res[p,q] inv2[q,x]
    for (int t = tid; t < M1 * W; t += 256) {
        int p = t / W, x = t % W;
        float2 acc = make_float2(0.f, 0.f);
        for (int q = 0; q < M2; q++) acc = cmadd(sres[p * M2 + q], sinv2[q * W + x], acc);
        sT[t] = acc;
    }
    __syncthreads();
    // S[o,x] = sum_p inv1[p,o] * T[p,x]
    float2* sp = &g_S[(size_t)pk * HW];
    for (int t = tid; t < HW; t += 256) {
        int o = t / W, x = t % W;
        float2 acc = make_float2(0.f, 0.f);
        for (int p = 0; p < M1; p++) acc = cmadd(sinv1[p * H + o], sT[p * W + x], acc);
        sp[t] = acc;
    }
}

// ---------------- k_res1 v3: 2b x 4k register tile ----------------
// res1[b,k,hw] = sum_i alpha[b,i,hw] * S[i,k,hw].
// grid 672 = 8 b-pairs * 12 k-quads * 7 hw-chunks; 8 cmadds per 6 loads (5x traffic cut).
__global__ __launch_bounds__(256) void k_res1() {
    int bid = blockIdx.x;
    int ch = bid % 7;
    int rest = bid / 7;                            // 0..95
    int kq = rest % 12, bp = rest / 12;            // bp 0..7
    int hw = ch * 256 + threadIdx.x;
    if (hw >= HW) return;
    int b0 = bp * 2, k0 = kq * 4;
    float2 acc[2][4];
#pragma unroll
    for (int u = 0; u < 2; u++)
#pragma unroll
        for (int v = 0; v < 4; v++) acc[u][v] = make_float2(0.f, 0.f);
    for (int i = 0; i < C; i++) {
        float2 a0 = g_alpha[(size_t)((b0    ) * C + i) * HW + hw];
        float2 a1 = g_alpha[(size_t)((b0 + 1) * C + i) * HW + hw];
        const float2* sp = &g_S[(size_t)(i * C + k0) * HW + hw];
        float2 s0 = sp[0];
        float2 s1 = sp[HW];
        float2 s2 = sp[2 * HW];
        float2 s3 = sp[3 * HW];
        acc[0][0] = cmadd(a0, s0, acc[0][0]);
        acc[0][1] = cmadd(a0, s1, acc[0][1]);
        acc[0][2] = cmadd(a0, s2, acc[0][2]);
        acc[0][3] = cmadd(a0, s3, acc[0][3]);
        acc[1][0] = cmadd(a1, s0, acc[1][0]);
        acc[1][1] = cmadd(a1, s1, acc[1][1]);
        acc[1][2] = cmadd(a1, s2, acc[1][2]);
        acc[1][3] = cmadd(a1, s3, acc[1][3]);
    }
#pragma unroll
    for (int u = 0; u < 2; u++)
#pragma unroll
        for (int v = 0; v < 4; v++)
            g_res1[(size_t)((b0 + u) * C + k0 + v) * HW + hw] = acc[u][v];
}

// ---------------- x1 = ifft2(res1).real, 2 outputs/thread ----------------
__global__ __launch_bounds__(256) void k_ifft() {
    int bid = blockIdx.x; int tid = threadIdx.x;
    __shared__ float2 s0[HW], s1[HW];
    const float2* rp = &g_res1[(size_t)bid * HW];
    for (int i = tid; i < HW; i += 256) s0[i] = rp[i];
    __syncthreads();
    // inverse over o, paired h: s1[h,x] = sum_o s0[o,x] * conj(wfh[o,h])
    for (int i = tid; i < 21 * W; i += 256) {
        int h0 = (i / W) * 2, x = i % W;
        bool pair = (h0 + 1) < H;
        float2 a0 = make_float2(0.f, 0.f), a1 = make_float2(0.f, 0.f);
        for (int o = 0; o < H; o++) {
            float2 v = s0[o * W + x];
            float2 t0 = g_wfh[o * H + h0];
            a0.x = fmaf(v.x, t0.x, fmaf(v.y, t0.y, a0.x));
            a0.y = fmaf(v.y, t0.x, fmaf(-v.x, t0.y, a0.y));
            if (pair) {
                float2 t1 = g_wfh[o * H + h0 + 1];
                a1.x = fmaf(v.x, t1.x, fmaf(v.y, t1.y, a1.x));
                a1.y = fmaf(v.y, t1.x, fmaf(-v.x, t1.y, a1.y));
            }
        }
        s1[h0 * W + x] = a0;
        if (pair) s1[(h0 + 1) * W + x] = a1;
    }
    __syncthreads();
    // inverse over x, paired w, real part only
    float* xp = &g_x1[(size_t)bid * HW];
    for (int i = tid; i < H * 20; i += 256) {
        int h = i / 20, w0 = (i % 20) * 2;
        float a0 = 0.f, a1 = 0.f;
        for (int x = 0; x < W; x++) {
            float2 v = s1[h * W + x];
            float2 t0 = g_wfw[x * W + w0];
            float2 t1 = g_wfw[x * W + w0 + 1];
            a0 = fmaf(v.x, t0.x, fmaf(v.y, t0.y, a0));
            a1 = fmaf(v.x, t1.x, fmaf(v.y, t1.y, a1));
        }
        xp[h * W + w0]     = a0 * (1.0f / (H * W));
        xp[h * W + w0 + 1] = a1 * (1.0f / (H * W));
    }
}

// ---------------- k_r2a v4: per (i,k,b-chunk): Zr = res ⊙ (inv1 @ alpha @ inv2^T) ----------
// grid C*C*4 = 9216. Y: 160 thr (4b x 40x), 12 accs, float4 inv1t reads. Z: 192 thr.
// LDS ~21KB -> 7 blocks/CU. 3 barriers per block.
__global__ __launch_bounds__(256) void k_r2a(const float* __restrict__ res_in, int l) {
    // XCD-aware remap: same-i blocks on one XCD (alpha[:,i] slices L2-resident)
    int bid = blockIdx.x;
    int xcd = bid & 7, idx = bid >> 3;             // idx 0..1151
    int i = (idx / (C * 4)) * 8 + xcd;             // 6 i's per XCD
    int rem = idx % (C * 4);
    int k = rem >> 2;
    int bc = rem & 3;                              // b-chunk: b = bc*4 .. bc*4+3
    int pk = i * C + k;
    int tid = threadIdx.x;
    __shared__ float2 sY[4 * M1 * 41];             // 15.7 KB
    __shared__ float2 si1t[H * 16];                // transposed inv1 [o][p], 16-padded
    __shared__ float2 si2[M2 * 41];                // [q*41 + x]
    __shared__ float2 sres[M1 * M2];
    for (int t = tid; t < H * 16; t += 256) si1t[t] = g_inv1t[(size_t)pk * (H * 16) + t];
    for (int t = tid; t < M2 * W; t += 256) {
        int q = t / W, x = t % W;
        si2[q * 41 + x] = g_inv2[(size_t)pk * (M2 * W) + t];
    }
    const float2* rp = (const float2*)res_in + (size_t)(l * C * C + pk) * M1 * M2;
    for (int t = tid; t < M1 * M2; t += 256) sres[t] = rp[t];
    __syncthreads();
    // ---- Y phase ----
    if (tid < 160) {
        int bloc = tid / 40, x = tid % 40;
        int b = bc * 4 + bloc;
        const float2* ap = &g_alpha[(size_t)(b * C + i) * HW + x];
        float2 yacc[12];
#pragma unroll
        for (int p = 0; p < 12; p++) yacc[p] = make_float2(0.f, 0.f);
        for (int o = 0; o < H; o++) {
            float2 a = ap[o * W];
            const float4* e4 = (const float4*)&si1t[o * 16];
#pragma unroll
            for (int j = 0; j < 6; j++) {
                float4 ee = e4[j];
                yacc[2 * j]     = cmadd(make_float2(ee.x, ee.y), a, yacc[2 * j]);
                yacc[2 * j + 1] = cmadd(make_float2(ee.z, ee.w), a, yacc[2 * j + 1]);
            }
        }
#pragma unroll
        for (int p = 0; p < 12; p++) sY[(bloc * M1 + p) * 41 + x] = yacc[p];
    }
    __syncthreads();
    // ---- Z phase ----
    if (tid < 192) {
        int bloc = tid / 48, rem2 = tid % 48;
        int p = rem2 >> 2, qq = rem2 & 3;
        int q0 = qq * 3;
        float2 zacc[3];
#pragma unroll
        for (int j = 0; j < 3; j++) zacc[j] = make_float2(0.f, 0.f);
        const float2* yrow = &sY[(bloc * M1 + p) * 41];
        for (int x = 0; x < W; x++) {
            float2 y = yrow[x];
#pragma unroll
            for (int j = 0; j < 3; j++) zacc[j] = cmadd(y, si2[(q0 + j) * 41 + x], zacc[j]);
        }
        int b = bc * 4 + bloc;
        float2* out = &g_Zr[pk][b * (M1 * M2) + p * M2 + q0];
#pragma unroll
        for (int j = 0; j < 3; j++) out[j] = cmul(sres[p * M2 + q0 + j], zacc[j]);
    }
}

// ---------------- k_r2b: r2[b,k,p,q] = sum_i Zr[i*C+k][b,p,q] ----------------
__global__ __launch_bounds__(256) void k_r2b() {
    int t = blockIdx.x * 256 + threadIdx.x;        // < B*C*144
    if (t >= B * C * M1 * M2) return;
    int pq = t % (M1 * M2);
    int k = (t / (M1 * M2)) % C;
    int b = t / (M1 * M2 * C);
    float2 acc = make_float2(0.f, 0.f);
    for (int i = 0; i < C; i++) {
        float2 v = g_Zr[i * C + k][b * (M1 * M2) + pq];
        acc.x += v.x; acc.y += v.y;
    }
    g_r2[(size_t)(b * C + k) * (M1 * M2) + pq] = acc;
}

// ---------------- k_x2p: partial x2 over 16-ci chunk (part 0..2) ----------------
// grid 2304 = 8(xcd) * 3(part) * 96(k-chunk*b); LDS ~26KB -> 6 blocks/CU.
constexpr int XNCI = 2;
__global__ __launch_bounds__(256) void k_x2p() {
    int bid = blockIdx.x;
    int xcd = bid & 7, rest = bid >> 3;            // 0..287
    int part = rest % 3;
    int idx = rest / 3;                            // 0..95
    int k = (idx / B) * 8 + xcd;
    int b = idx % B;
    int tid = threadIdx.x;
    __shared__ float2 sE1[XNCI * M1 * 44];         // [jp][z], z-padded to 44 (zeros)
    __shared__ float2 sV [XNCI * M1 * 40];         // [jp][x]
    __shared__ float2 sE2[XNCI * M2 * 41];         // [jq][x]
    __shared__ float2 sr2[XNCI * M1 * M2];
    int xh = tid % 20, zq = tid / 20;              // active: tid<240
    int x0 = xh * 2, z0 = zq * 4;
    float accr[4][2];
#pragma unroll
    for (int zi = 0; zi < 4; zi++) { accr[zi][0] = 0.f; accr[zi][1] = 0.f; }

    int cg0 = part * (C / XNCI / 3);               // 8 cg groups per part
    for (int cg = cg0; cg < cg0 + C / XNCI / 3; cg++) {
        for (int t = tid; t < XNCI * M1 * 44; t += 256) {
            int j = t / (M1 * 44), rem = t % (M1 * 44);
            int p = rem / 44, z = rem % 44;
            sE1[t] = (z < H) ? g_E1[(size_t)((cg * XNCI + j) * C + k) * (M1 * H) + p * H + z]
                             : make_float2(0.f, 0.f);
        }
        for (int t = tid; t < XNCI * M2 * W; t += 256) {
            int j = t / (M2 * W), rem = t % (M2 * W);
            sE2[(t / W) * 41 + (t % W)] = g_E2[(size_t)((cg * XNCI + j) * C + k) * (M2 * W) + rem];
        }
        for (int t = tid; t < XNCI * M1 * M2; t += 256) {
            int j = t / (M1 * M2);
            sr2[t] = g_r2[(size_t)(b * C + cg * XNCI + j) * (M1 * M2) + (t % (M1 * M2))];
        }
        __syncthreads();
        // V[jp][x] = sum_q r2[j][p,q] * E2[j][q,x]
        for (int r = 0; r < 4; r++) {
            int id = tid + r * 256;
            if (id < XNCI * M1 * W) {
                int j = id / (M1 * W), rem = id % (M1 * W);
                int p = rem / W, x = rem % W;
                float2 a = make_float2(0.f, 0.f);
#pragma unroll
                for (int q = 0; q < M2; q++)
                    a = cmadd(sr2[j * (M1 * M2) + p * M2 + q], sE2[(j * M2 + q) * 41 + x], a);
                sV[(j * M1 + p) * 40 + x] = a;
            }
        }
        __syncthreads();
        // accr[z,x] += Re( E1[jp][z] * V[jp][x] )
        if (tid < 240 && z0 < H) {
            for (int jp = 0; jp < XNCI * M1; jp++) {
                float4 v  = *(const float4*)&sV[jp * 40 + x0];
                float4 eA = *(const float4*)&sE1[jp * 44 + z0];
                float4 eB = *(const float4*)&sE1[jp * 44 + z0 + 2];
                accr[0][0] = fmaf(eA.x, v.x, fmaf(-eA.y, v.y, accr[0][0]));
                accr[0][1] = fmaf(eA.x, v.z, fmaf(-eA.y, v.w, accr[0][1]));
                accr[1][0] = fmaf(eA.z, v.x, fmaf(-eA.w, v.y, accr[1][0]));
                accr[1][1] = fmaf(eA.z, v.z, fmaf(-eA.w, v.w, accr[1][1]));
                accr[2][0] = fmaf(eB.x, v.x, fmaf(-eB.y, v.y, accr[2][0]));
                accr[2][1] = fmaf(eB.x, v.z, fmaf(-eB.y, v.w, accr[2][1]));
                accr[3][0] = fmaf(eB.z, v.x, fmaf(-eB.w, v.y, accr[3][0]));
                accr[3][1] = fmaf(eB.z, v.z, fmaf(-eB.w, v.w, accr[3][1]));
            }
        }
        __syncthreads();
    }
    float* op = &g_xpart[part][b * C + k][0];
    if (tid < 240 && z0 < H) {
#pragma unroll
        for (int zi = 0; zi < 4; zi++) {
            int z = z0 + zi;
            if (z < H) { op[z * W + x0] = accr[zi][0]; op[z * W + x0 + 1] = accr[zi][1]; }
        }
    }
}

// ---------------- k_fin: pr = x1 + (sum parts)/(H*W); stats ----------------
__global__ __launch_bounds__(256) void k_fin() {
    int bid = blockIdx.x;                          // b*C + k
    int tid = threadIdx.x;
    __shared__ float red[8];
    float* xp = &g_x1[(size_t)bid * HW];
    const float* p0 = &g_xpart[0][bid][0];
    const float* p1 = &g_xpart[1][bid][0];
    const float* p2 = &g_xpart[2][bid][0];
    float s = 0.f, ss = 0.f;
    for (int i = tid; i < HW; i += 256) {
        float v = xp[i] + (p0[i] + p1[i] + p2[i]) * (1.0f / (H * W));
        xp[i] = v; s += v; ss += v * v;
    }
    for (int off = 32; off; off >>= 1) { s += __shfl_down(s, off); ss += __shfl_down(ss, off); }
    if ((tid & 63) == 0) { red[tid >> 6] = s; red[4 + (tid >> 6)] = ss; }
    __syncthreads();
    if (tid == 0) {
        float S = red[0] + red[1] + red[2] + red[3];
        float SS = red[4] + red[5] + red[6] + red[7];
        float mean = S * (1.0f / HW);
        float var = SS * (1.0f / HW) - mean * mean;
        g_mu[bid] = mean; g_rstd[bid] = rsqrtf(var + EPS);
    }
}

// ---------------- h_next = sin( inorm(pr) + conv(h) + conv_b ) ----------------
constexpr int TILE = 128;
constexpr int NTILE = (HW + TILE - 1) / TILE;   // 13
__global__ __launch_bounds__(256) void k_comb(const float* __restrict__ cw,
                                              const float* __restrict__ cb, int l, int src) {
    int b = blockIdx.x / NTILE;
    int t0 = (blockIdx.x % NTILE) * TILE;
    int tid = threadIdx.x;
    __shared__ float shh[C * TILE];
    __shared__ float scw[C * C];
    __shared__ float smu[C], srs[C], scb[C];
    for (int i = tid; i < C * C; i += 256) scw[i] = cw[l * C * C + i];
    for (int i = tid; i < C; i += 256) {
        smu[i] = g_mu[b * C + i]; srs[i] = g_rstd[b * C + i]; scb[i] = cb[l * C + i];
    }
    for (int i = tid; i < C * TILE; i += 256) {
        int c = i / TILE, t = i % TILE; int hw = t0 + t;
        shh[i] = (hw < HW) ? g_h[src][(size_t)(b * C + c) * HW + hw] : 0.f;
    }
    __syncthreads();
    for (int i = tid; i < C * TILE; i += 256) {
        int o = i / TILE, t = i % TILE; int hw = t0 + t;
        if (hw >= HW) continue;
        float acc = scb[o];
        for (int ci = 0; ci < C; ci++) acc = fmaf(scw[o * C + ci], shh[ci * TILE + t], acc);
        float prn = (g_x1[(size_t)(b * C + o) * HW + hw] - smu[o]) * srs[o];
        g_h[src ^ 1][(size_t)(b * C + o) * HW + hw] = sinf(prn + acc);
    }
}

// ---------------- head: out = fc2( sin(fc1(h)) ) ----------------
__global__ __launch_bounds__(256) void k_head(const float* __restrict__ w1, const float* __restrict__ b1,
                                              const float* __restrict__ w2, const float* __restrict__ b2,
                                              float* __restrict__ out, int src) {
    __shared__ float sw1[128 * C];
    __shared__ float sb1[128], sw2[2 * 128];
    int tid = threadIdx.x;
    for (int i = tid; i < 128 * C; i += 256) sw1[i] = w1[i];
    for (int i = tid; i < 128; i += 256) sb1[i] = b1[i];
    for (int i = tid; i < 256; i += 256) sw2[i] = w2[i];
    __syncthreads();
    int pt = blockIdx.x * 256 + tid;               // b*HW + hw
    if (pt >= B * HW) return;
    int b = pt / HW, hw = pt % HW;
    float hv[C];
#pragma unroll
    for (int c = 0; c < C; c++) hv[c] = g_h[src][(size_t)(b * C + c) * HW + hw];
    float o0 = b2[0], o1 = b2[1];
    for (int j = 0; j < 128; j++) {
        float a = sb1[j];
#pragma unroll
        for (int c = 0; c < C; c++) a = fmaf(sw1[j * C + c], hv[c], a);
        float sv = sinf(a);
        o0 = fmaf(sw2[j], sv, o0);
        o1 = fmaf(sw2[128 + j], sv, o1);
    }
    out[pt * 2 + 0] = o0; out[pt * 2 + 1] = o1;
}

// ---------------- launcher ----------------
extern "C" void kernel_launch(void* const* d_in, const int* in_sizes, int n_in,
                              void* d_out, int out_size, void* d_ws, size_t ws_size,
                              hipStream_t stream) {
    const float* x    = (const float*)d_in[0];
    const float* fc0w = (const float*)d_in[1];
    const float* fc0b = (const float*)d_in[2];
    const float* p1   = (const float*)d_in[3];
    const float* p2   = (const float*)d_in[4];
    const float* res  = (const float*)d_in[5];
    const float* cw   = (const float*)d_in[6];
    const float* cb   = (const float*)d_in[7];
    const float* w1   = (const float*)d_in[8];
    const float* b1   = (const float*)d_in[9];
    const float* w2   = (const float*)d_in[10];
    const float* b2   = (const float*)d_in[11];
    float* out = (float*)d_out;

    k_tw<<<(H * H + W * W + 255) / 256, 256, 0, stream>>>();
    k_fc0<<<(B * C * HW + 255) / 256, 256, 0, stream>>>(x, fc0w, fc0b);
    int src = 0;
    for (int l = 0; l < NL; l++) {
        k_fft<<<B * C, 256, 0, stream>>>(src);
        k_tbS<<<C * C, 256, 0, stream>>>(p1, p2, res, l);
        k_res1<<<672, 256, 0, stream>>>();
        k_ifft<<<B * C, 256, 0, stream>>>();
        k_r2a<<<C * C * 4, 256, 0, stream>>>(res, l);
        k_r2b<<<(B * C * M1 * M2 + 255) / 256, 256, 0, stream>>>();
        k_x2p<<<3 * B * C, 256, 0, stream>>>();
        k_fin<<<B * C, 256, 0, stream>>>();
        k_comb<<<B * NTILE, 256, 0, stream>>>(cw, cb, l, src);
        src ^= 1;
    }
    k_head<<<(B * HW + 255) / 256, 256, 0, stream>>>(w1, b1, w2, b2, out, src);
}